// Round 4
// baseline (257.840 us; speedup 1.0000x reference)
//
#include <hip/hip_runtime.h>
#include <hip/hip_bf16.h>

// SelfOtherAwareAttention: B=4, L=S=2048, D=256, H=8, hd=32
// qp/kp in workspace: [B*2048][512] bf16, cols 0:256 = self-proj, 256:512 = other-proj
// scale (hd^-0.5) folded into qp.

typedef __attribute__((ext_vector_type(8))) __bf16 bf16x8;
typedef __attribute__((ext_vector_type(4))) float f32x4;
typedef __attribute__((ext_vector_type(4))) int i32x4;

#define MFMA16(a, b, c) __builtin_amdgcn_mfma_f32_16x16x32_bf16((a), (b), (c), 0, 0, 0)

__device__ __forceinline__ bf16x8 load8_f32_to_bf16(const float* __restrict__ p) {
    float4 f0 = *(const float4*)p;
    float4 f1 = *(const float4*)(p + 4);
    bf16x8 r;
    r[0] = (__bf16)f0.x; r[1] = (__bf16)f0.y; r[2] = (__bf16)f0.z; r[3] = (__bf16)f0.w;
    r[4] = (__bf16)f1.x; r[5] = (__bf16)f1.y; r[6] = (__bf16)f1.z; r[7] = (__bf16)f1.w;
    return r;
}

// ---------------- Fused projections: q-side and k-side in one dispatch ----------------
// out[m, c] = (in[m,:] . W[c,:]) * scale ;  W = Ws rows for c<256, Wo rows for c>=256.
// Per side: M=8192, N=512, K=256. grid (8, 128): y<64 -> q side, y>=64 -> k side.
__global__ __launch_bounds__(256) void proj_kernel(
    const float* __restrict__ qin, const float* __restrict__ kin,
    const float* __restrict__ Wqs, const float* __restrict__ Wqo,
    const float* __restrict__ Wks, const float* __restrict__ Wko,
    __bf16* __restrict__ qout, __bf16* __restrict__ kout)
{
    const bool isK = blockIdx.y >= 64;
    const float* in = isK ? kin : qin;
    const float* Ws = isK ? Wks : Wqs;
    const float* Wo = isK ? Wko : Wqo;
    __bf16* outp    = isK ? kout : qout;
    const float scale = isK ? 1.0f : 0.17677669529663687f;  // 32^-0.5

    const int n0 = blockIdx.x * 64;
    const int m0 = (blockIdx.y & 63) * 128;
    const int tid  = threadIdx.x;
    const int lane = tid & 63;
    const int w    = tid >> 6;
    const int wr = w >> 1, wc = w & 1;
    const int l15 = lane & 15, l4 = lane >> 4;

    f32x4 acc[4][2];
#pragma unroll
    for (int mi = 0; mi < 4; ++mi)
#pragma unroll
        for (int ni = 0; ni < 2; ++ni) acc[mi][ni] = (f32x4){0.f, 0.f, 0.f, 0.f};

    const int arow0 = m0 + wr * 64 + l15;  // + mi*16

    const float* wptr[2];
#pragma unroll
    for (int ni = 0; ni < 2; ++ni) {
        int c = n0 + wc * 32 + ni * 16 + l15;
        wptr[ni] = (c < 256) ? (Ws + c * 256) : (Wo + (c - 256) * 256);
    }

#pragma unroll
    for (int ks = 0; ks < 8; ++ks) {
        const int k0 = ks * 32 + l4 * 8;
        bf16x8 a[4], b[2];
#pragma unroll
        for (int mi = 0; mi < 4; ++mi)
            a[mi] = load8_f32_to_bf16(in + (arow0 + mi * 16) * 256 + k0);
#pragma unroll
        for (int ni = 0; ni < 2; ++ni)
            b[ni] = load8_f32_to_bf16(wptr[ni] + k0);
#pragma unroll
        for (int mi = 0; mi < 4; ++mi)
#pragma unroll
            for (int ni = 0; ni < 2; ++ni)
                acc[mi][ni] = MFMA16(a[mi], b[ni], acc[mi][ni]);
    }

    // C/D layout: col = lane&15, row = (lane>>4)*4 + j
#pragma unroll
    for (int mi = 0; mi < 4; ++mi)
#pragma unroll
        for (int ni = 0; ni < 2; ++ni)
#pragma unroll
            for (int j = 0; j < 4; ++j) {
                int row = m0 + wr * 64 + mi * 16 + l4 * 4 + j;
                int col = n0 + wc * 32 + ni * 16 + l15;
                outp[row * 512 + col] = (__bf16)(acc[mi][ni][j] * scale);
            }
}

// ---------------- Fused attention (barrier-free wave-local LDS transpose) ----------------
// grid (S/64=32, L/128=16, B=4), block 256 (4 waves; wave owns 32 l-rows x 64 s-cols).
// mfma(A=k_frag, B=q_frag): D col = lane&15 -> l, D row = (lane>>4)*4+j -> s.
// Each wave transposes ITS OWN 32x64 tile through a private LDS region, then stores
// its own rows fully coalesced (16 lanes = one 256B contiguous row segment).
// Same-wave LDS write->read ordering is handled by lgkmcnt; NO __syncthreads anywhere,
// so global stores drain asynchronously and waves free-run across h.
__global__ __launch_bounds__(256, 3) void attn_kernel(
    const __bf16* __restrict__ qp, const __bf16* __restrict__ kp,
    const int* __restrict__ som, const float* __restrict__ mask,
    float* __restrict__ out)
{
    __shared__ float tile[4][32][68];

    const int s0 = blockIdx.x * 64;
    const int l0 = blockIdx.y * 128;
    const int b  = blockIdx.z;
    const int lane = threadIdx.x & 63;
    const int w    = threadIdx.x >> 6;
    const int l15 = lane & 15, l4 = lane >> 4;

    const int lrow0 = l0 + w * 32 + l15;   // + mi*16       (l index of this thread)
    const int scol0 = s0 + l4 * 4;         // + ni*16 (+j)  (s index, 16B aligned)

    // ---- per-block setup: mask + som in the transposed C/D layout ----
    f32x4 mreg[2][4];
    unsigned int sbits = 0;
#pragma unroll
    for (int mi = 0; mi < 2; ++mi)
#pragma unroll
        for (int ni = 0; ni < 4; ++ni) {
            int idx = (b * 2048 + lrow0 + mi * 16) * 2048 + scol0 + ni * 16;
            f32x4 m  = __builtin_nontemporal_load((const f32x4*)(mask + idx));
            i32x4 sm = __builtin_nontemporal_load((const i32x4*)(som + idx));
            mreg[mi][ni] = m;
            const int t0 = (mi * 4 + ni) * 4;
#pragma unroll
            for (int j = 0; j < 4; ++j)
                sbits |= (sm[j] != 0) ? (1u << (t0 + j)) : 0u;
        }

    // fragment bases
    const __bf16* qbase = qp + (b * 2048 + lrow0) * 512 + l4 * 8;     // B operand (l rows)
    const __bf16* kbase = kp + (b * 2048 + s0 + l15) * 512 + l4 * 8;  // A operand (s rows)

    float (*mytile)[68] = tile[w];

    for (int h = 0; h < 8; ++h) {
        const int hofs = h * 32;
        bf16x8 qb[2][2], ka[4][2];
#pragma unroll
        for (int mi = 0; mi < 2; ++mi)
#pragma unroll
            for (int p = 0; p < 2; ++p)
                qb[mi][p] = *(const bf16x8*)(qbase + mi * 16 * 512 + p * 256 + hofs);
#pragma unroll
        for (int ni = 0; ni < 4; ++ni)
#pragma unroll
            for (int p = 0; p < 2; ++p)
                ka[ni][p] = *(const bf16x8*)(kbase + ni * 16 * 512 + p * 256 + hofs);

        // compute -> private LDS region (rows = l15 + mi*16, cols = l4*4 + ni*16)
#pragma unroll
        for (int mi = 0; mi < 2; ++mi)
#pragma unroll
            for (int ni = 0; ni < 4; ++ni) {
                f32x4 z = (f32x4){0.f, 0.f, 0.f, 0.f};
                f32x4 as = MFMA16(ka[ni][0], qb[mi][0], z);   // self
                f32x4 ao = MFMA16(ka[ni][1], qb[mi][1], z);   // other
                const int t0 = (mi * 4 + ni) * 4;
                f32x4 v;
#pragma unroll
                for (int j = 0; j < 4; ++j)
                    v[j] = (((sbits >> (t0 + j)) & 1u) ? as[j] : ao[j]) + mreg[mi][ni][j];
                *(f32x4*)&mytile[l15 + mi * 16][l4 * 4 + ni * 16] = v;
            }

        // wave-local coalesced stores: this wave's own 32 rows
        const long obase = ((long)(b * 8 + h) * 2048 + l0 + w * 32) * 2048 + s0;
#pragma unroll
        for (int p = 0; p < 8; ++p) {
            int r = p * 4 + l4;                       // row within wave's 32
            f32x4 v = *(const f32x4*)&mytile[r][l15 * 4];
            *(f32x4*)(out + obase + (long)r * 2048 + l15 * 4) = v;
        }
    }
}

extern "C" void kernel_launch(void* const* d_in, const int* in_sizes, int n_in,
                              void* d_out, int out_size, void* d_ws, size_t ws_size,
                              hipStream_t stream) {
    const float* q    = (const float*)d_in[0];
    const float* k    = (const float*)d_in[1];
    const int*   som  = (const int*)d_in[2];
    const float* mask = (const float*)d_in[3];
    const float* Wqs  = (const float*)d_in[4];
    const float* Wqo  = (const float*)d_in[5];
    const float* Wks  = (const float*)d_in[6];
    const float* Wko  = (const float*)d_in[7];
    float* out = (float*)d_out;

    __bf16* qp = (__bf16*)d_ws;            // [8192][512]
    __bf16* kp = qp + 8192 * 512;          // [8192][512]

    dim3 pgrid(8, 128, 1), pblk(256, 1, 1);
    hipLaunchKernelGGL(proj_kernel, pgrid, pblk, 0, stream,
                       q, k, Wqs, Wqo, Wks, Wko, qp, kp);

    dim3 agrid(32, 16, 4), ablk(256, 1, 1);
    hipLaunchKernelGGL(attn_kernel, agrid, ablk, 0, stream, qp, kp, som, mask, out);
}

// Round 5
// 203.716 us; speedup vs baseline: 1.2657x; 1.2657x over previous
//
#include <hip/hip_runtime.h>
#include <hip/hip_bf16.h>

// SelfOtherAwareAttention: B=4, L=S=2048, D=256, H=8, hd=32
// qp/kp in workspace: [B*2048][512] bf16, cols 0:256 = self-proj, 256:512 = other-proj
// scale (hd^-0.5) folded into qp.

typedef __attribute__((ext_vector_type(8))) __bf16 bf16x8;
typedef __attribute__((ext_vector_type(4))) float f32x4;
typedef __attribute__((ext_vector_type(4))) int i32x4;

#define MFMA16(a, b, c) __builtin_amdgcn_mfma_f32_16x16x32_bf16((a), (b), (c), 0, 0, 0)

__device__ __forceinline__ bf16x8 load8_f32_to_bf16(const float* __restrict__ p) {
    float4 f0 = *(const float4*)p;
    float4 f1 = *(const float4*)(p + 4);
    bf16x8 r;
    r[0] = (__bf16)f0.x; r[1] = (__bf16)f0.y; r[2] = (__bf16)f0.z; r[3] = (__bf16)f0.w;
    r[4] = (__bf16)f1.x; r[5] = (__bf16)f1.y; r[6] = (__bf16)f1.z; r[7] = (__bf16)f1.w;
    return r;
}

// ---------------- Fused projections: q-side and k-side in one dispatch ----------------
// out[m, c] = (in[m,:] . W[c,:]) * scale ;  W = Ws rows for c<256, Wo rows for c>=256.
// Per side: M=8192, N=512, K=256. grid (8, 128): y<64 -> q side, y>=64 -> k side.
__global__ __launch_bounds__(256) void proj_kernel(
    const float* __restrict__ qin, const float* __restrict__ kin,
    const float* __restrict__ Wqs, const float* __restrict__ Wqo,
    const float* __restrict__ Wks, const float* __restrict__ Wko,
    __bf16* __restrict__ qout, __bf16* __restrict__ kout)
{
    const bool isK = blockIdx.y >= 64;
    const float* in = isK ? kin : qin;
    const float* Ws = isK ? Wks : Wqs;
    const float* Wo = isK ? Wko : Wqo;
    __bf16* outp    = isK ? kout : qout;
    const float scale = isK ? 1.0f : 0.17677669529663687f;  // 32^-0.5

    const int n0 = blockIdx.x * 64;
    const int m0 = (blockIdx.y & 63) * 128;
    const int tid  = threadIdx.x;
    const int lane = tid & 63;
    const int w    = tid >> 6;
    const int wr = w >> 1, wc = w & 1;
    const int l15 = lane & 15, l4 = lane >> 4;

    f32x4 acc[4][2];
#pragma unroll
    for (int mi = 0; mi < 4; ++mi)
#pragma unroll
        for (int ni = 0; ni < 2; ++ni) acc[mi][ni] = (f32x4){0.f, 0.f, 0.f, 0.f};

    const int arow0 = m0 + wr * 64 + l15;  // + mi*16

    const float* wptr[2];
#pragma unroll
    for (int ni = 0; ni < 2; ++ni) {
        int c = n0 + wc * 32 + ni * 16 + l15;
        wptr[ni] = (c < 256) ? (Ws + c * 256) : (Wo + (c - 256) * 256);
    }

#pragma unroll
    for (int ks = 0; ks < 8; ++ks) {
        const int k0 = ks * 32 + l4 * 8;
        bf16x8 a[4], b[2];
#pragma unroll
        for (int mi = 0; mi < 4; ++mi)
            a[mi] = load8_f32_to_bf16(in + (arow0 + mi * 16) * 256 + k0);
#pragma unroll
        for (int ni = 0; ni < 2; ++ni)
            b[ni] = load8_f32_to_bf16(wptr[ni] + k0);
#pragma unroll
        for (int mi = 0; mi < 4; ++mi)
#pragma unroll
            for (int ni = 0; ni < 2; ++ni)
                acc[mi][ni] = MFMA16(a[mi], b[ni], acc[mi][ni]);
    }

    // C/D layout: col = lane&15, row = (lane>>4)*4 + j
#pragma unroll
    for (int mi = 0; mi < 4; ++mi)
#pragma unroll
        for (int ni = 0; ni < 2; ++ni)
#pragma unroll
            for (int j = 0; j < 4; ++j) {
                int row = m0 + wr * 64 + mi * 16 + l4 * 4 + j;
                int col = n0 + wc * 32 + ni * 16 + l15;
                outp[row * 512 + col] = (__bf16)(acc[mi][ni][j] * scale);
            }
}

// ---------------- Fused attention (wide-row tile: 32l x 256s) ----------------
// grid (S/256=8, L/32=64, B=4), block 256 = 4 waves; wave w owns 32l x 64s at
// s-offset w*64. mfma(A=k_frag, B=q_frag): D col=lane&15 -> l, row=(lane>>4)*4+j -> s.
// Epilogue: compute tile -> LDS [32][260] -> stores where ONE wave instruction
// writes ONE full 1KB contiguous row-slice. Mask/som staged through the same LDS
// with 1KB-coalesced global reads.
__global__ __launch_bounds__(256) void attn_kernel(
    const __bf16* __restrict__ qp, const __bf16* __restrict__ kp,
    const int* __restrict__ som, const float* __restrict__ mask,
    float* __restrict__ out)
{
    __shared__ float tile[32][260];   // stride 260 floats: both phases at b128 bank floor

    const int s0 = blockIdx.x * 256;
    const int l0 = blockIdx.y * 32;
    const int b  = blockIdx.z;
    const int tid  = threadIdx.x;
    const int lane = tid & 63;
    const int w    = tid >> 6;
    const int l15 = lane & 15, l4 = lane >> 4;

    // compute-layout coordinates (block-local): row = l15 + mi*16, col = w*64 + l4*4 + ni*16
    const int c_row = l15;
    const int c_col = w * 64 + l4 * 4;

    // ---- stage mask, then som, through LDS: coalesced 1KB reads -> compute-layout regs ----
    f32x4 mreg[2][4];
    unsigned int sbits = 0;
#pragma unroll
    for (int i = 0; i < 8; ++i) {
        int r = i * 4 + w;
        f32x4 m = __builtin_nontemporal_load(
            (const f32x4*)(mask + (long)(b * 2048 + l0 + r) * 2048 + s0 + 4 * lane));
        *(f32x4*)&tile[r][4 * lane] = m;
    }
    __syncthreads();
#pragma unroll
    for (int mi = 0; mi < 2; ++mi)
#pragma unroll
        for (int ni = 0; ni < 4; ++ni)
            mreg[mi][ni] = *(const f32x4*)&tile[c_row + mi * 16][c_col + ni * 16];
    __syncthreads();
#pragma unroll
    for (int i = 0; i < 8; ++i) {
        int r = i * 4 + w;
        i32x4 sm = __builtin_nontemporal_load(
            (const i32x4*)(som + (long)(b * 2048 + l0 + r) * 2048 + s0 + 4 * lane));
        *(i32x4*)&tile[r][4 * lane] = sm;
    }
    __syncthreads();
#pragma unroll
    for (int mi = 0; mi < 2; ++mi)
#pragma unroll
        for (int ni = 0; ni < 4; ++ni) {
            i32x4 sm = *(const i32x4*)&tile[c_row + mi * 16][c_col + ni * 16];
            const int t0 = (mi * 4 + ni) * 4;
#pragma unroll
            for (int j = 0; j < 4; ++j)
                sbits |= (sm[j] != 0) ? (1u << (t0 + j)) : 0u;
        }
    __syncthreads();

    // fragment bases: q rows = l (l0 + l15 + mi*16), k rows = s (s0 + w*64 + l15 + ni*16)
    const __bf16* qbase = qp + (long)(b * 2048 + l0 + l15) * 512 + l4 * 8;
    const __bf16* kbase = kp + (long)(b * 2048 + s0 + w * 64 + l15) * 512 + l4 * 8;

    for (int h = 0; h < 8; ++h) {
        const int hofs = h * 32;
        bf16x8 qb[2][2], ka[4][2];
#pragma unroll
        for (int mi = 0; mi < 2; ++mi)
#pragma unroll
            for (int p = 0; p < 2; ++p)
                qb[mi][p] = *(const bf16x8*)(qbase + mi * 16 * 512 + p * 256 + hofs);
#pragma unroll
        for (int ni = 0; ni < 4; ++ni)
#pragma unroll
            for (int p = 0; p < 2; ++p)
                ka[ni][p] = *(const bf16x8*)(kbase + ni * 16 * 512 + p * 256 + hofs);

        // compute -> LDS (compute layout)
#pragma unroll
        for (int mi = 0; mi < 2; ++mi)
#pragma unroll
            for (int ni = 0; ni < 4; ++ni) {
                f32x4 z = (f32x4){0.f, 0.f, 0.f, 0.f};
                f32x4 as = MFMA16(ka[ni][0], qb[mi][0], z);   // self
                f32x4 ao = MFMA16(ka[ni][1], qb[mi][1], z);   // other
                const int t0 = (mi * 4 + ni) * 4;
                f32x4 v;
#pragma unroll
                for (int j = 0; j < 4; ++j)
                    v[j] = (((sbits >> (t0 + j)) & 1u) ? as[j] : ao[j]) + mreg[mi][ni][j];
                *(f32x4*)&tile[c_row + mi * 16][c_col + ni * 16] = v;
            }

        __syncthreads();

        // store: one wave instruction = one full 1KB contiguous row-slice
        const long obase = (long)((b * 8 + h) * 2048 + l0) * 2048 + s0;
#pragma unroll
        for (int i = 0; i < 8; ++i) {
            int r = i * 4 + w;
            f32x4 v = *(const f32x4*)&tile[r][4 * lane];
            *(f32x4*)(out + obase + (long)r * 2048 + 4 * lane) = v;
        }

        __syncthreads();
    }
}

extern "C" void kernel_launch(void* const* d_in, const int* in_sizes, int n_in,
                              void* d_out, int out_size, void* d_ws, size_t ws_size,
                              hipStream_t stream) {
    const float* q    = (const float*)d_in[0];
    const float* k    = (const float*)d_in[1];
    const int*   som  = (const int*)d_in[2];
    const float* mask = (const float*)d_in[3];
    const float* Wqs  = (const float*)d_in[4];
    const float* Wqo  = (const float*)d_in[5];
    const float* Wks  = (const float*)d_in[6];
    const float* Wko  = (const float*)d_in[7];
    float* out = (float*)d_out;

    __bf16* qp = (__bf16*)d_ws;            // [8192][512]
    __bf16* kp = qp + 8192 * 512;          // [8192][512]

    dim3 pgrid(8, 128, 1), pblk(256, 1, 1);
    hipLaunchKernelGGL(proj_kernel, pgrid, pblk, 0, stream,
                       q, k, Wqs, Wqo, Wks, Wko, qp, kp);

    dim3 agrid(8, 64, 4), ablk(256, 1, 1);
    hipLaunchKernelGGL(attn_kernel, agrid, ablk, 0, stream, qp, kp, som, mask, out);
}